// Round 4
// baseline (305.902 us; speedup 1.0000x reference)
//
#include <hip/hip_runtime.h>
#include <hip/hip_bf16.h>
#include <math.h>

#define HIDDEN 2048
#define NHEADS 16
#define NKV 4
#define HD 128
#define SEQ 2048
#define BATCH 2
#define MTOT (BATCH*SEQ)     // 4096
#define NQ (NHEADS*HD)       // 2048
#define NKVD (NKV*HD)        // 512
#define NQKV (NQ + 2*NKVD)   // 3072

typedef __attribute__((ext_vector_type(8))) short short8;
typedef __attribute__((ext_vector_type(4))) float float4v;

#if __has_builtin(__builtin_amdgcn_exp2f)
#define EXP2F __builtin_amdgcn_exp2f
#else
#define EXP2F exp2f
#endif
#define C1 0.1275174f   // (1/sqrt(128)) * log2(e)

static __device__ __forceinline__ unsigned short f2bf(float f) {
  union { float f; unsigned int u; } v; v.f = f;
  unsigned int r = v.u + 0x7FFF + ((v.u >> 16) & 1);
  return (unsigned short)(r >> 16);
}
static __device__ __forceinline__ float bf2f(unsigned short h) {
  union { unsigned int u; float f; } v; v.u = ((unsigned int)h) << 16;
  return v.f;
}

// async global->LDS, 16B per lane; LDS dest = uniform base + lane*16
static __device__ __forceinline__ void async16(const unsigned short* g, unsigned short* l) {
  __builtin_amdgcn_global_load_lds(
      (const __attribute__((address_space(1))) unsigned int*)g,
      (__attribute__((address_space(3))) unsigned int*)l, 16, 0, 0);
}

// ---------------- cast fp32 -> bf16 (vectorized x4) ----------------
__global__ void cast_f32_bf16(const float* __restrict__ in,
                              unsigned short* __restrict__ out, int n) {
  int i = (blockIdx.x * blockDim.x + threadIdx.x) * 4;
  if (i < n) {
    float4 v = *(const float4*)(in + i);
    ushort4 o;
    o.x = f2bf(v.x); o.y = f2bf(v.y); o.z = f2bf(v.z); o.w = f2bf(v.w);
    *(ushort4*)(out + i) = o;
  }
}

// ---------------- transpose + cast: W[K][N] fp32 -> Wt[N][K] bf16 ----------------
__global__ void transpose_cast(const float* __restrict__ W,
                               unsigned short* __restrict__ Wt, int K, int N) {
  __shared__ float tile[32][33];
  int tn = blockIdx.x * 32;
  int tk = blockIdx.y * 32;
  int tx = threadIdx.x & 31;
  int ty = threadIdx.x >> 5;  // 0..7
  #pragma unroll
  for (int i = 0; i < 4; i++) {
    int k = tk + ty + i * 8;
    tile[ty + i * 8][tx] = W[(size_t)k * N + tn + tx];
  }
  __syncthreads();
  #pragma unroll
  for (int i = 0; i < 4; i++) {
    int n = tn + ty + i * 8;
    Wt[(size_t)n * K + tk + tx] = f2bf(tile[tx][ty + i * 8]);
  }
}

// ---------------- RoPE in place on [B][S][nheads][128] bf16 ----------------
__global__ void rope_kernel(unsigned short* __restrict__ Qb, int nheads) {
  int idx = blockIdx.x * blockDim.x + threadIdx.x;
  int d = idx & 63;
  int hr = idx >> 6;                 // (b*SEQ + s)*nheads + h
  int spos = (hr / nheads) % SEQ;
  size_t base = (size_t)hr * HD;
  float inv = exp2f((float)d * -0.2076205059304601f);  // 10000^(-d/64)
  float ang = (float)spos * inv;
  float sn, cs;
  sincosf(ang, &sn, &cs);
  float q1 = bf2f(Qb[base + d]);
  float q2 = bf2f(Qb[base + d + 64]);
  Qb[base + d]      = f2bf(q1 * cs - q2 * sn);
  Qb[base + d + 64] = f2bf(q2 * cs + q1 * sn);
}

// ================= fused QKV GEMM, 256^2 tile, 4-deep counted-vmcnt ring =========
// Round-3: reverted prefetch depth to 2 (depth-3 measured 68.4 vs depth-2's 66.4).
// BK=32 tiles in a 4-slot LDS ring (128 KiB), stage issued 2 tiles ahead,
// s_waitcnt vmcnt(4) (never 0 mid-loop) + raw s_barrier once per tile.
// 8 waves (2M x 4N), per-wave 128x64 output. V-blocks (bx>=10) use operand-swapped
// MFMA so V^T stores stay row-coalesced.
__global__ __launch_bounds__(512, 2) void gemm_qkv(
    const unsigned short* __restrict__ A,
    const unsigned short* __restrict__ Bt,
    unsigned short* __restrict__ Qb,
    unsigned short* __restrict__ Kb,
    unsigned short* __restrict__ Vt) {
  // ring slot: [A 256x32 | B 256x32] shorts = 32 KiB; x4 slots = 128 KiB
  __shared__ __align__(16) unsigned short L[4 * 16384];
  const int K = HIDDEN;          // 2048
  const int NT = K / 32;         // 64 K-tiles
  int bm = blockIdx.y * 256, bn = blockIdx.x * 256;
  int tid = threadIdx.x, w = tid >> 6, lane = tid & 63;
  int wrow = w >> 2, wcol = w & 3;           // 2M x 4N wave grid
  int m16 = lane & 15, quad = lane >> 4;
  int lrow = lane >> 2, lch = lane & 3;
  int lchs = lch ^ ((lrow >> 1) & 3);        // swizzled staging piece
  int qx = quad ^ ((m16 >> 1) & 3);          // swizzled read piece
  const unsigned short* Ag = A + (size_t)(bm + w * 32 + lrow) * K + lchs * 8;
  const unsigned short* Bg = Bt + (size_t)(bn + w * 32 + lrow) * K + lchs * 8;

  float4v acc[8][4];
  #pragma unroll
  for (int i = 0; i < 8; i++)
    #pragma unroll
    for (int j = 0; j < 4; j++) acc[i][j] = (float4v)0.0f;

  auto stage = [&](int t) {
    unsigned short* Lb = L + (t & 3) * 16384;
    int k0 = t * 32;
    #pragma unroll
    for (int i = 0; i < 2; i++) {
      async16(Ag + (size_t)i * 16 * K + k0, Lb + w * 1024 + i * 512);
      async16(Bg + (size_t)i * 16 * K + k0, Lb + 8192 + w * 1024 + i * 512);
    }
  };

  const bool isV = (blockIdx.x >= 10);

  // prologue: tiles 0 and 1 in flight; wait tile 0 (own 4 oldest), barrier
  stage(0); stage(1);
  asm volatile("s_waitcnt vmcnt(4)" ::: "memory");
  __builtin_amdgcn_s_barrier();
  __builtin_amdgcn_sched_barrier(0);

  if (!isV) {
    for (int t = 0; t < NT; ++t) {
      if (t + 2 < NT) stage(t + 2);
      const unsigned short* Ab_ = L + (t & 3) * 16384;
      const unsigned short* Bb_ = Ab_ + 8192;
      short8 af[8], bfr[4];
      #pragma unroll
      for (int i = 0; i < 8; i++)
        af[i] = *(const short8*)(&Ab_[(wrow * 128 + i * 16 + m16) * 32 + qx * 8]);
      #pragma unroll
      for (int j = 0; j < 4; j++)
        bfr[j] = *(const short8*)(&Bb_[(wcol * 64 + j * 16 + m16) * 32 + qx * 8]);
      __builtin_amdgcn_s_setprio(1);
      #pragma unroll
      for (int i = 0; i < 8; i++)
        #pragma unroll
        for (int j = 0; j < 4; j++)
          acc[i][j] = __builtin_amdgcn_mfma_f32_16x16x32_bf16(af[i], bfr[j], acc[i][j], 0, 0, 0);
      __builtin_amdgcn_s_setprio(0);
      if (t + 2 < NT) { asm volatile("s_waitcnt vmcnt(4)" ::: "memory"); }
      else            { asm volatile("s_waitcnt vmcnt(0)" ::: "memory"); }
      __builtin_amdgcn_s_barrier();
      __builtin_amdgcn_sched_barrier(0);
    }
  } else {
    for (int t = 0; t < NT; ++t) {
      if (t + 2 < NT) stage(t + 2);
      const unsigned short* Ab_ = L + (t & 3) * 16384;
      const unsigned short* Bb_ = Ab_ + 8192;
      short8 af[8], bfr[4];
      #pragma unroll
      for (int i = 0; i < 8; i++)
        af[i] = *(const short8*)(&Ab_[(wrow * 128 + i * 16 + m16) * 32 + qx * 8]);
      #pragma unroll
      for (int j = 0; j < 4; j++)
        bfr[j] = *(const short8*)(&Bb_[(wcol * 64 + j * 16 + m16) * 32 + qx * 8]);
      __builtin_amdgcn_s_setprio(1);
      #pragma unroll
      for (int i = 0; i < 8; i++)
        #pragma unroll
        for (int j = 0; j < 4; j++)
          acc[i][j] = __builtin_amdgcn_mfma_f32_16x16x32_bf16(bfr[j], af[i], acc[i][j], 0, 0, 0);
      __builtin_amdgcn_s_setprio(0);
      if (t + 2 < NT) { asm volatile("s_waitcnt vmcnt(4)" ::: "memory"); }
      else            { asm volatile("s_waitcnt vmcnt(0)" ::: "memory"); }
      __builtin_amdgcn_s_barrier();
      __builtin_amdgcn_sched_barrier(0);
    }
  }

  if (blockIdx.x < 8) {
    #pragma unroll
    for (int i = 0; i < 8; i++)
      #pragma unroll
      for (int j = 0; j < 4; j++)
        #pragma unroll
        for (int r = 0; r < 4; r++) {
          int row = bm + wrow * 128 + i * 16 + quad * 4 + r;
          int col = bn + wcol * 64 + j * 16 + m16;
          Qb[(size_t)row * NQ + col] = f2bf(acc[i][j][r]);
        }
  } else if (!isV) {
    #pragma unroll
    for (int i = 0; i < 8; i++)
      #pragma unroll
      for (int j = 0; j < 4; j++)
        #pragma unroll
        for (int r = 0; r < 4; r++) {
          int row = bm + wrow * 128 + i * 16 + quad * 4 + r;
          int col = bn - 2048 + wcol * 64 + j * 16 + m16;
          Kb[(size_t)row * NKVD + col] = f2bf(acc[i][j][r]);
        }
  } else {
    // swapped layout: row(quad*4+r) = f-tile j, col(m16) = m-tile i
    #pragma unroll
    for (int i = 0; i < 8; i++)
      #pragma unroll
      for (int j = 0; j < 4; j++)
        #pragma unroll
        for (int r = 0; r < 4; r++) {
          int f = bn - 2560 + wcol * 64 + j * 16 + quad * 4 + r;
          int m = bm + wrow * 128 + i * 16 + m16;
          Vt[(size_t)f * MTOT + m] = f2bf(acc[i][j][r]);
        }
  }
}

// ================= O-projection GEMM (dbuf + swizzle, fp32 out) =================
__global__ __launch_bounds__(256) void gemm_o(
    const unsigned short* __restrict__ A,
    const unsigned short* __restrict__ Bt,
    float* __restrict__ C, int M, int N, int K) {
  __shared__ unsigned short As0[128 * 32], Bs0[128 * 32];
  __shared__ unsigned short As1[128 * 32], Bs1[128 * 32];
  int bm = blockIdx.y * 128, bn = blockIdx.x * 128;
  int tid = threadIdx.x, w = tid >> 6, lane = tid & 63;
  int wm = (w >> 1) * 64, wn = (w & 1) * 64;
  int m16 = lane & 15, quad = lane >> 4;
  int lrow = lane >> 2, lch = lane & 3;
  int lchs = lch ^ ((lrow >> 1) & 3);
  int qx = quad ^ ((m16 >> 1) & 3);
  const unsigned short* Ag = A + (size_t)(bm + w * 32 + lrow) * K + lchs * 8;
  const unsigned short* Bg = Bt + (size_t)(bn + w * 32 + lrow) * K + lchs * 8;
  int woff = w * 1024;

  float4v acc[4][4];
  #pragma unroll
  for (int i = 0; i < 4; i++)
    #pragma unroll
    for (int j = 0; j < 4; j++) acc[i][j] = (float4v)0.0f;

  auto stage = [&](int k0, unsigned short* Asl, unsigned short* Bsl) {
    #pragma unroll
    for (int i = 0; i < 2; i++) {
      async16(Ag + (size_t)i * 16 * K + k0, Asl + woff + i * 512);
      async16(Bg + (size_t)i * 16 * K + k0, Bsl + woff + i * 512);
    }
  };
  auto compute = [&](const unsigned short* As, const unsigned short* Bs) {
    short8 af[4], bfr[4];
    #pragma unroll
    for (int i = 0; i < 4; i++)
      af[i] = *(const short8*)(&As[(wm + i * 16 + m16) * 32 + qx * 8]);
    #pragma unroll
    for (int j = 0; j < 4; j++)
      bfr[j] = *(const short8*)(&Bs[(wn + j * 16 + m16) * 32 + qx * 8]);
    #pragma unroll
    for (int i = 0; i < 4; i++)
      #pragma unroll
      for (int j = 0; j < 4; j++)
        acc[i][j] = __builtin_amdgcn_mfma_f32_16x16x32_bf16(af[i], bfr[j], acc[i][j], 0, 0, 0);
  };

  stage(0, As0, Bs0);
  for (int k0 = 0; k0 < K; k0 += 64) {
    __syncthreads();
    if (k0 + 32 < K) stage(k0 + 32, As1, Bs1);
    compute(As0, Bs0);
    __syncthreads();
    if (k0 + 64 < K) stage(k0 + 64, As0, Bs0);
    compute(As1, Bs1);
  }

  #pragma unroll
  for (int i = 0; i < 4; i++)
    #pragma unroll
    for (int j = 0; j < 4; j++)
      #pragma unroll
      for (int r = 0; r < 4; r++) {
        int row = bm + wm + i * 16 + quad * 4 + r;
        int col = bn + wn + j * 16 + m16;
        C[(size_t)row * N + col] = acc[i][j][r];
      }
}

// ---------------- Flash attention: 48 KiB LDS -> 3 blocks/CU (TLP) --------------
// Round-3 theory: latency-bound (MfmaUtil 21 / VALUBusy 30 / HBM 10%), only
// 2 waves/SIMD -> serial softmax+shuffle chain and barriers leave the SIMD idle.
// Fix: single K buffer + single V buffer + Ps = 48 KiB -> 3 blocks/CU (3 waves/
// SIMD, +50% TLP). Intra-block prefetch cover is given up; cross-block TLP covers
// the (mostly L2-hit) K/V load latency instead. Schedule per tile:
//   vmcnt(0)+barrier (K,V ready) -> S-MFMA -> softmax -> P fence -> PV
//   -> lgkmcnt(0)+barrier (reads retired) -> issue K(kt+1),V(kt+1)
// T5 setprio around MFMA clusters; T13 defer-max rescale (exact math, P <= 2^8).
#define FLASH_TILE()                                                          \
  {                                                                           \
    const int ktb = kt * 64;                                                  \
    asm volatile("s_waitcnt vmcnt(0)" ::: "memory");                          \
    __builtin_amdgcn_s_barrier(); /* DATA: K(kt),V(kt) visible in LDS */      \
    __builtin_amdgcn_sched_barrier(0);                                        \
    const bool act1 = (ktb <= lmax_w);                                        \
    float4v sacc[2][4];                                                       \
    _Pragma("unroll") for (int s4 = 0; s4 < 4; s4++) {                        \
      sacc[0][s4] = (float4v)0.0f; sacc[1][s4] = (float4v)0.0f; }             \
    __builtin_amdgcn_s_setprio(1);                                            \
    if (act1) {                                                               \
      _Pragma("unroll")                                                       \
      for (int s4 = 0; s4 < 4; s4++)                                          \
        _Pragma("unroll")                                                     \
        for (int c = 0; c < 4; c++) {                                         \
          short8 kf = *(const short8*)(&Ks[c * 2048 + (s4 * 16 + m16) * 32 + qx * 8]); \
          sacc[0][s4] = __builtin_amdgcn_mfma_f32_16x16x32_bf16(kf, qf[0][c], sacc[0][s4], 0, 0, 0); \
          sacc[1][s4] = __builtin_amdgcn_mfma_f32_16x16x32_bf16(kf, qf[1][c], sacc[1][s4], 0, 0, 0); \
        }                                                                     \
    } else {                                                                  \
      _Pragma("unroll")                                                       \
      for (int s4 = 0; s4 < 4; s4++)                                          \
        _Pragma("unroll")                                                     \
        for (int c = 0; c < 4; c++) {                                         \
          short8 kf = *(const short8*)(&Ks[c * 2048 + (s4 * 16 + m16) * 32 + qx * 8]); \
          sacc[0][s4] = __builtin_amdgcn_mfma_f32_16x16x32_bf16(kf, qf[0][c], sacc[0][s4], 0, 0, 0); \
        }                                                                     \
    }                                                                         \
    __builtin_amdgcn_s_setprio(0);                                            \
    _Pragma("unroll")                                                         \
    for (int qs = 0; qs < 2; qs++) {                                          \
      if (qs == 0 || act1) {                                                  \
        const int tb = qs ? L : H;                                            \
        const int qabs = tb * 64 + w * 16 + m16;                              \
        const bool diag = (kt == tb);                                         \
        float sv[4][4]; float mloc = -1e30f;                                  \
        if (diag) {                                                           \
          _Pragma("unroll") for (int s4 = 0; s4 < 4; s4++)                    \
            _Pragma("unroll") for (int r = 0; r < 4; r++) {                   \
              int kabs = ktb + s4 * 16 + quad * 4 + r;                        \
              float t = sacc[qs][s4][r];                                      \
              sv[s4][r] = (kabs > qabs) ? -1e30f : t;                         \
              mloc = fmaxf(mloc, sv[s4][r]); }                                \
        } else {                                                              \
          _Pragma("unroll") for (int s4 = 0; s4 < 4; s4++)                    \
            _Pragma("unroll") for (int r = 0; r < 4; r++) {                   \
              sv[s4][r] = sacc[qs][s4][r]; mloc = fmaxf(mloc, sv[s4][r]); }   \
        }                                                                     \
        mloc *= C1;                                                           \
        mloc = fmaxf(mloc, __shfl_xor(mloc, 16, 64));                         \
        mloc = fmaxf(mloc, __shfl_xor(mloc, 32, 64));                         \
        float mnewS = fmaxf(miS[qs], mloc);                                   \
        const bool defer = (bool)__all(mloc <= miS[qs] + 8.0f);               \
        if (defer) mnewS = miS[qs]; /* T13: keep old max, P bounded by 2^8 */ \
        const int prow = qs * 64 + w * 16 + m16;                              \
        const int psw = prow * 32; const int rx = prow & 7;                   \
        float rs = 0.0f;                                                      \
        _Pragma("unroll") for (int s4 = 0; s4 < 4; s4++) {                    \
          float p0 = EXP2F(__builtin_fmaf(sv[s4][0], C1, -mnewS));            \
          float p1 = EXP2F(__builtin_fmaf(sv[s4][1], C1, -mnewS));            \
          float p2 = EXP2F(__builtin_fmaf(sv[s4][2], C1, -mnewS));            \
          float p3 = EXP2F(__builtin_fmaf(sv[s4][3], C1, -mnewS));            \
          rs += p0 + p1 + p2 + p3;                                            \
          uint2 u;                                                            \
          u.x = (__float_as_uint(p1) & 0xffff0000u) | (__float_as_uint(p0) >> 16); \
          u.y = (__float_as_uint(p3) & 0xffff0000u) | (__float_as_uint(p2) >> 16); \
          int chunkW = s4 * 2 + (quad >> 1);                                  \
          *(uint2*)(&Ps[psw + ((chunkW ^ rx) << 2) + (quad & 1) * 2]) = u;    \
        }                                                                     \
        rs += __shfl_xor(rs, 16, 64);                                         \
        rs += __shfl_xor(rs, 32, 64);                                         \
        if (!defer) {                                                         \
          const float alpha = EXP2F(miS[qs] - mnewS);                         \
          li[qs] *= alpha; miS[qs] = mnewS;                                   \
          _Pragma("unroll") for (int ds = 0; ds < 8; ds++) oacc[ds][qs] *= alpha; \
        }                                                                     \
        li[qs] += rs;                                                         \
      }                                                                       \
    }                                                                         \
    asm volatile("s_waitcnt lgkmcnt(0)" ::: "memory"); /* P visible (wave-local) */ \
    __builtin_amdgcn_sched_barrier(0);                                        \
    {                                                                         \
      const int r0 = w * 16 + m16, r1 = 64 + w * 16 + m16;                    \
      __builtin_amdgcn_s_setprio(1);                                          \
      if (act1) {                                                             \
        _Pragma("unroll")                                                     \
        for (int kc = 0; kc < 2; kc++) {                                      \
          short8 pf0 = *(const short8*)(&Ps[r0 * 32 + (((kc * 4 + quad) ^ (r0 & 7)) << 2)]); \
          short8 pf1 = *(const short8*)(&Ps[r1 * 32 + (((kc * 4 + quad) ^ (r1 & 7)) << 2)]); \
          _Pragma("unroll")                                                   \
          for (int ds = 0; ds < 8; ds++) {                                    \
            short8 vf = *(const short8*)(&Vs[kc * 4096 + (ds * 16 + m16) * 32 + qx * 8]); \
            oacc[ds][0] = __builtin_amdgcn_mfma_f32_16x16x32_bf16(vf, pf0, oacc[ds][0], 0, 0, 0); \
            oacc[ds][1] = __builtin_amdgcn_mfma_f32_16x16x32_bf16(vf, pf1, oacc[ds][1], 0, 0, 0); \
          }                                                                   \
        }                                                                     \
      } else {                                                                \
        _Pragma("unroll")                                                     \
        for (int kc = 0; kc < 2; kc++) {                                      \
          short8 pf0 = *(const short8*)(&Ps[r0 * 32 + (((kc * 4 + quad) ^ (r0 & 7)) << 2)]); \
          _Pragma("unroll")                                                   \
          for (int ds = 0; ds < 8; ds++) {                                    \
            short8 vf = *(const short8*)(&Vs[kc * 4096 + (ds * 16 + m16) * 32 + qx * 8]); \
            oacc[ds][0] = __builtin_amdgcn_mfma_f32_16x16x32_bf16(vf, pf0, oacc[ds][0], 0, 0, 0); \
          }                                                                   \
        }                                                                     \
      }                                                                       \
      __builtin_amdgcn_s_setprio(0);                                          \
    }                                                                         \
    asm volatile("s_waitcnt lgkmcnt(0)" ::: "memory"); /* all LDS reads retired */ \
    __builtin_amdgcn_s_barrier(); /* WAR: safe to overwrite K,V */            \
    __builtin_amdgcn_sched_barrier(0);                                        \
    if (kt < H) {                                                             \
      const unsigned short* Vg = Vt + vgrow * (size_t)MTOT                    \
                                    + (size_t)b * SEQ + (ktb + 64) + kcv * 32 + vlch * 8; \
      unsigned short* Vl = Vs + kcv * 4096 + ipv * 512;                       \
      _Pragma("unroll")                                                       \
      for (int i = 0; i < 4; i++) async16(Vg + (size_t)i * 16 * MTOT, Vl + i * 512); \
      const unsigned short* Kg = Kp + (((size_t)b * SEQ + (kt + 1) * 64 + lrow) * NKV + kvh) * HD + w * 32 + vlch * 8; \
      unsigned short* Kl = Ks + w * 2048;                                     \
      _Pragma("unroll")                                                       \
      for (int i = 0; i < 4; i++) async16(Kg + (size_t)i * 16 * NKV * HD, Kl + i * 512); \
    }                                                                         \
  }

__global__ __launch_bounds__(256, 3) void flash_attn(
    const unsigned short* __restrict__ Q,
    const unsigned short* __restrict__ Kp,
    const unsigned short* __restrict__ Vt,
    unsigned short* __restrict__ O) {
  __shared__ unsigned short Ks[4 * 64 * 32];   // 16 KB [dchunk][key][32d]
  __shared__ unsigned short Vs[2 * 128 * 32];  // 16 KB [kchunk][d][32seq]
  __shared__ unsigned int   Ps[128 * 32];      // 16 KB swizzled P[q][k/2]

  int bx = blockIdx.x;            // 0..15
  int h  = blockIdx.y;
  int b  = blockIdx.z;
  int kvh = h >> 2;
  int H = 31 - bx, L = bx;
  int tid = threadIdx.x;
  int w = tid >> 6, lane = tid & 63;
  int m16 = lane & 15, quad = lane >> 4;
  int lrow = lane >> 2, lch = lane & 3;
  const int vlch = lch ^ ((lrow >> 1) & 3);   // swizzled staging piece
  const int qx = quad ^ ((m16 >> 1) & 3);     // swizzled read piece
  const int lmax_w = L * 64 + w * 16 + 15;    // qs=1 active while ktb <= lmax_w

  const int kcv = w >> 1, ipv = (w & 1) * 4;
  const size_t vgrow = (size_t)kvh * HD + ipv * 16 + lrow;

  // qs=0 -> H-tile rows [H*64 + w*16, +16); qs=1 -> L-tile rows [L*64 + w*16, +16)
  short8 qf[2][4];
  #pragma unroll
  for (int qs = 0; qs < 2; qs++) {
    int tb = qs ? L : H;
    size_t qbase = (((size_t)b * SEQ + tb * 64 + w * 16 + m16) * NHEADS + h) * HD;
    #pragma unroll
    for (int c = 0; c < 4; c++)
      qf[qs][c] = *(const short8*)(Q + qbase + c * 32 + quad * 8);
  }

  float4v oacc[8][2];
  #pragma unroll
  for (int ds = 0; ds < 8; ds++) { oacc[ds][0] = (float4v)0.0f; oacc[ds][1] = (float4v)0.0f; }
  float miS[2] = {-1e30f, -1e30f}, li[2] = {0.0f, 0.0f};

  // prologue: stage V(0) and K(0) (retired at first DATA wait)
  {
    const unsigned short* Vg = Vt + vgrow * (size_t)MTOT + (size_t)b * SEQ + kcv * 32 + vlch * 8;
    unsigned short* Vl = Vs + kcv * 4096 + ipv * 512;
    #pragma unroll
    for (int i = 0; i < 4; i++) async16(Vg + (size_t)i * 16 * MTOT, Vl + i * 512);
    const unsigned short* Kg = Kp + (((size_t)b * SEQ + lrow) * NKV + kvh) * HD + w * 32 + vlch * 8;
    unsigned short* Kl = Ks + w * 2048;
    #pragma unroll
    for (int i = 0; i < 4; i++) async16(Kg + (size_t)i * 16 * NKV * HD, Kl + i * 512);
  }

  for (int kt = 0; kt <= H; ++kt) {
    FLASH_TILE()
  }

  #pragma unroll
  for (int qs = 0; qs < 2; qs++) {
    float inv = 1.0f / li[qs];
    int tb = qs ? L : H;
    int qabs = tb * 64 + w * 16 + m16;
    size_t obase = (((size_t)b * SEQ + qabs) * NHEADS + h) * HD + quad * 4;
    #pragma unroll
    for (int ds = 0; ds < 8; ds++) {
      float v0 = oacc[ds][qs][0] * inv;
      float v1 = oacc[ds][qs][1] * inv;
      float v2 = oacc[ds][qs][2] * inv;
      float v3 = oacc[ds][qs][3] * inv;
      uint2 u;
      u.x = ((unsigned)f2bf(v1) << 16) | f2bf(v0);
      u.y = ((unsigned)f2bf(v3) << 16) | f2bf(v2);
      *(uint2*)(O + obase + ds * 16) = u;
    }
  }
}

extern "C" void kernel_launch(void* const* d_in, const int* in_sizes, int n_in,
                              void* d_out, int out_size, void* d_ws, size_t ws_size,
                              hipStream_t stream) {
  const float* x  = (const float*)d_in[0];
  const float* Wq = (const float*)d_in[1];
  const float* Wk = (const float*)d_in[2];
  const float* Wv = (const float*)d_in[3];
  const float* Wo = (const float*)d_in[4];
  float* out = (float*)d_out;

  unsigned short* ws = (unsigned short*)d_ws;
  unsigned short* xb  = ws;                              // [4096][2048]
  unsigned short* Wqt = xb  + (size_t)MTOT * HIDDEN;     // [2048][2048] (Wqt/Wkt/Wvt contiguous = Wqkvt)
  unsigned short* Wkt = Wqt + (size_t)NQ * HIDDEN;       // [512][2048]
  unsigned short* Wvt = Wkt + (size_t)NKVD * HIDDEN;     // [512][2048]
  unsigned short* Wot = Wvt + (size_t)NKVD * HIDDEN;     // [2048][2048]
  unsigned short* Qb  = Wot + (size_t)NQ * HIDDEN;       // [4096][2048]
  unsigned short* Kb  = Qb  + (size_t)MTOT * NQ;         // [4096][512]
  unsigned short* Vtb = Kb  + (size_t)MTOT * NKVD;       // [512][4096]  (V^T)
  unsigned short* Ab  = Vtb + (size_t)MTOT * NKVD;       // [4096][2048]

  cast_f32_bf16<<<(MTOT * HIDDEN / 4 + 255) / 256, 256, 0, stream>>>(x, xb, MTOT * HIDDEN);
  transpose_cast<<<dim3(NQ / 32, HIDDEN / 32), 256, 0, stream>>>(Wq, Wqt, HIDDEN, NQ);
  transpose_cast<<<dim3(NKVD / 32, HIDDEN / 32), 256, 0, stream>>>(Wk, Wkt, HIDDEN, NKVD);
  transpose_cast<<<dim3(NKVD / 32, HIDDEN / 32), 256, 0, stream>>>(Wv, Wvt, HIDDEN, NKVD);
  transpose_cast<<<dim3(NQ / 32, HIDDEN / 32), 256, 0, stream>>>(Wo, Wot, NQ, HIDDEN);

  gemm_qkv<<<dim3(NQKV / 256, MTOT / 256), 512, 0, stream>>>(xb, Wqt, Qb, Kb, Vtb);

  rope_kernel<<<(BATCH * SEQ * NHEADS * 64) / 256, 256, 0, stream>>>(Qb, NHEADS);
  rope_kernel<<<(BATCH * SEQ * NKV * 64) / 256, 256, 0, stream>>>(Kb, NKV);

  flash_attn<<<dim3(16, NHEADS, BATCH), 256, 0, stream>>>(Qb, Kb, Vtb, Ab);

  gemm_o<<<dim3(HIDDEN / 128, MTOT / 128), 256, 0, stream>>>(Ab, Wot, out, MTOT, HIDDEN, NQ);
}

// Round 5
// 286.299 us; speedup vs baseline: 1.0685x; 1.0685x over previous
//
#include <hip/hip_runtime.h>
#include <hip/hip_bf16.h>
#include <math.h>

#define HIDDEN 2048
#define NHEADS 16
#define NKV 4
#define HD 128
#define SEQ 2048
#define BATCH 2
#define MTOT (BATCH*SEQ)     // 4096
#define NQ (NHEADS*HD)       // 2048
#define NKVD (NKV*HD)        // 512
#define NQKV (NQ + 2*NKVD)   // 3072

typedef __attribute__((ext_vector_type(8))) short short8;
typedef __attribute__((ext_vector_type(4))) float float4v;

#if __has_builtin(__builtin_amdgcn_exp2f)
#define EXP2F __builtin_amdgcn_exp2f
#else
#define EXP2F exp2f
#endif
#define C1 0.1275174f   // (1/sqrt(128)) * log2(e)

static __device__ __forceinline__ unsigned short f2bf(float f) {
  union { float f; unsigned int u; } v; v.f = f;
  unsigned int r = v.u + 0x7FFF + ((v.u >> 16) & 1);
  return (unsigned short)(r >> 16);
}
static __device__ __forceinline__ float bf2f(unsigned short h) {
  union { unsigned int u; float f; } v; v.u = ((unsigned int)h) << 16;
  return v.f;
}

// async global->LDS, 16B per lane; LDS dest = uniform base + lane*16
static __device__ __forceinline__ void async16(const unsigned short* g, unsigned short* l) {
  __builtin_amdgcn_global_load_lds(
      (const __attribute__((address_space(1))) unsigned int*)g,
      (__attribute__((address_space(3))) unsigned int*)l, 16, 0, 0);
}

// ---------------- cast fp32 -> bf16 (vectorized x4) ----------------
__global__ void cast_f32_bf16(const float* __restrict__ in,
                              unsigned short* __restrict__ out, int n) {
  int i = (blockIdx.x * blockDim.x + threadIdx.x) * 4;
  if (i < n) {
    float4 v = *(const float4*)(in + i);
    ushort4 o;
    o.x = f2bf(v.x); o.y = f2bf(v.y); o.z = f2bf(v.z); o.w = f2bf(v.w);
    *(ushort4*)(out + i) = o;
  }
}

// -------- merged transpose+cast for all four weights (K=2048 for all) ----------
// bx 0..63 -> Wq (N=2048), 64..79 -> Wk (N=512), 80..95 -> Wv (N=512),
// 96..159 -> Wo (N=2048). Same 32x32 LDS-tile body as the verified single kernel.
__global__ void transpose_cast_all(
    const float* __restrict__ Wq, const float* __restrict__ Wk,
    const float* __restrict__ Wv, const float* __restrict__ Wo,
    unsigned short* __restrict__ Wqt, unsigned short* __restrict__ Wkt,
    unsigned short* __restrict__ Wvt, unsigned short* __restrict__ Wot) {
  __shared__ float tile[32][33];
  const int K = 2048;
  int bx = blockIdx.x;
  const float* W; unsigned short* Wt; int N; int tn;
  if (bx < 64)      { W = Wq; Wt = Wqt; N = NQ;     tn = bx * 32; }
  else if (bx < 80) { W = Wk; Wt = Wkt; N = NKVD;   tn = (bx - 64) * 32; }
  else if (bx < 96) { W = Wv; Wt = Wvt; N = NKVD;   tn = (bx - 80) * 32; }
  else              { W = Wo; Wt = Wot; N = HIDDEN; tn = (bx - 96) * 32; }
  int tk = blockIdx.y * 32;
  int tx = threadIdx.x & 31;
  int ty = threadIdx.x >> 5;  // 0..7
  #pragma unroll
  for (int i = 0; i < 4; i++) {
    int k = tk + ty + i * 8;
    tile[ty + i * 8][tx] = W[(size_t)k * N + tn + tx];
  }
  __syncthreads();
  #pragma unroll
  for (int i = 0; i < 4; i++) {
    int n = tn + ty + i * 8;
    Wt[(size_t)n * K + tk + tx] = f2bf(tile[tx][ty + i * 8]);
  }
}

// ---------------- merged RoPE for Q and K (one launch) ----------------
__global__ void rope_all(unsigned short* __restrict__ Qb,
                         unsigned short* __restrict__ Kb) {
  int idx = blockIdx.x * blockDim.x + threadIdx.x;
  const int QTOT = MTOT * NHEADS * 64;   // 4194304, multiple of 256
  unsigned short* P; int nheads;
  if (idx < QTOT) { P = Qb; nheads = NHEADS; }
  else            { P = Kb; nheads = NKV; idx -= QTOT; }
  int d = idx & 63;
  int hr = idx >> 6;                 // (b*SEQ + s)*nheads + h
  int spos = (hr / nheads) % SEQ;
  size_t base = (size_t)hr * HD;
  float inv = exp2f((float)d * -0.2076205059304601f);  // 10000^(-d/64)
  float ang = (float)spos * inv;
  float sn, cs;
  sincosf(ang, &sn, &cs);
  float q1 = bf2f(P[base + d]);
  float q2 = bf2f(P[base + d + 64]);
  P[base + d]      = f2bf(q1 * cs - q2 * sn);
  P[base + d + 64] = f2bf(q2 * cs + q1 * sn);
}

// ================= fused QKV GEMM, 256^2 tile, 4-deep counted-vmcnt ring =========
// Depth-2 (measured best: 66.4 vs depth-3's 68.4). BK=32 tiles in a 4-slot LDS
// ring (128 KiB), stage issued 2 tiles ahead, s_waitcnt vmcnt(4) (never 0
// mid-loop) + raw s_barrier once per tile. 8 waves (2M x 4N), per-wave 128x64
// output. V-blocks (bx>=10) use operand-swapped MFMA -> V^T stores row-coalesced.
__global__ __launch_bounds__(512, 2) void gemm_qkv(
    const unsigned short* __restrict__ A,
    const unsigned short* __restrict__ Bt,
    unsigned short* __restrict__ Qb,
    unsigned short* __restrict__ Kb,
    unsigned short* __restrict__ Vt) {
  // ring slot: [A 256x32 | B 256x32] shorts = 32 KiB; x4 slots = 128 KiB
  __shared__ __align__(16) unsigned short L[4 * 16384];
  const int K = HIDDEN;          // 2048
  const int NT = K / 32;         // 64 K-tiles
  int bm = blockIdx.y * 256, bn = blockIdx.x * 256;
  int tid = threadIdx.x, w = tid >> 6, lane = tid & 63;
  int wrow = w >> 2, wcol = w & 3;           // 2M x 4N wave grid
  int m16 = lane & 15, quad = lane >> 4;
  int lrow = lane >> 2, lch = lane & 3;
  int lchs = lch ^ ((lrow >> 1) & 3);        // swizzled staging piece
  int qx = quad ^ ((m16 >> 1) & 3);          // swizzled read piece
  const unsigned short* Ag = A + (size_t)(bm + w * 32 + lrow) * K + lchs * 8;
  const unsigned short* Bg = Bt + (size_t)(bn + w * 32 + lrow) * K + lchs * 8;

  float4v acc[8][4];
  #pragma unroll
  for (int i = 0; i < 8; i++)
    #pragma unroll
    for (int j = 0; j < 4; j++) acc[i][j] = (float4v)0.0f;

  auto stage = [&](int t) {
    unsigned short* Lb = L + (t & 3) * 16384;
    int k0 = t * 32;
    #pragma unroll
    for (int i = 0; i < 2; i++) {
      async16(Ag + (size_t)i * 16 * K + k0, Lb + w * 1024 + i * 512);
      async16(Bg + (size_t)i * 16 * K + k0, Lb + 8192 + w * 1024 + i * 512);
    }
  };

  const bool isV = (blockIdx.x >= 10);

  // prologue: tiles 0 and 1 in flight; wait tile 0 (own 4 oldest), barrier
  stage(0); stage(1);
  asm volatile("s_waitcnt vmcnt(4)" ::: "memory");
  __builtin_amdgcn_s_barrier();
  __builtin_amdgcn_sched_barrier(0);

  if (!isV) {
    for (int t = 0; t < NT; ++t) {
      if (t + 2 < NT) stage(t + 2);
      const unsigned short* Ab_ = L + (t & 3) * 16384;
      const unsigned short* Bb_ = Ab_ + 8192;
      short8 af[8], bfr[4];
      #pragma unroll
      for (int i = 0; i < 8; i++)
        af[i] = *(const short8*)(&Ab_[(wrow * 128 + i * 16 + m16) * 32 + qx * 8]);
      #pragma unroll
      for (int j = 0; j < 4; j++)
        bfr[j] = *(const short8*)(&Bb_[(wcol * 64 + j * 16 + m16) * 32 + qx * 8]);
      __builtin_amdgcn_s_setprio(1);
      #pragma unroll
      for (int i = 0; i < 8; i++)
        #pragma unroll
        for (int j = 0; j < 4; j++)
          acc[i][j] = __builtin_amdgcn_mfma_f32_16x16x32_bf16(af[i], bfr[j], acc[i][j], 0, 0, 0);
      __builtin_amdgcn_s_setprio(0);
      if (t + 2 < NT) { asm volatile("s_waitcnt vmcnt(4)" ::: "memory"); }
      else            { asm volatile("s_waitcnt vmcnt(0)" ::: "memory"); }
      __builtin_amdgcn_s_barrier();
      __builtin_amdgcn_sched_barrier(0);
    }
  } else {
    for (int t = 0; t < NT; ++t) {
      if (t + 2 < NT) stage(t + 2);
      const unsigned short* Ab_ = L + (t & 3) * 16384;
      const unsigned short* Bb_ = Ab_ + 8192;
      short8 af[8], bfr[4];
      #pragma unroll
      for (int i = 0; i < 8; i++)
        af[i] = *(const short8*)(&Ab_[(wrow * 128 + i * 16 + m16) * 32 + qx * 8]);
      #pragma unroll
      for (int j = 0; j < 4; j++)
        bfr[j] = *(const short8*)(&Bb_[(wcol * 64 + j * 16 + m16) * 32 + qx * 8]);
      __builtin_amdgcn_s_setprio(1);
      #pragma unroll
      for (int i = 0; i < 8; i++)
        #pragma unroll
        for (int j = 0; j < 4; j++)
          acc[i][j] = __builtin_amdgcn_mfma_f32_16x16x32_bf16(bfr[j], af[i], acc[i][j], 0, 0, 0);
      __builtin_amdgcn_s_setprio(0);
      if (t + 2 < NT) { asm volatile("s_waitcnt vmcnt(4)" ::: "memory"); }
      else            { asm volatile("s_waitcnt vmcnt(0)" ::: "memory"); }
      __builtin_amdgcn_s_barrier();
      __builtin_amdgcn_sched_barrier(0);
    }
  }

  if (blockIdx.x < 8) {
    #pragma unroll
    for (int i = 0; i < 8; i++)
      #pragma unroll
      for (int j = 0; j < 4; j++)
        #pragma unroll
        for (int r = 0; r < 4; r++) {
          int row = bm + wrow * 128 + i * 16 + quad * 4 + r;
          int col = bn + wcol * 64 + j * 16 + m16;
          Qb[(size_t)row * NQ + col] = f2bf(acc[i][j][r]);
        }
  } else if (!isV) {
    #pragma unroll
    for (int i = 0; i < 8; i++)
      #pragma unroll
      for (int j = 0; j < 4; j++)
        #pragma unroll
        for (int r = 0; r < 4; r++) {
          int row = bm + wrow * 128 + i * 16 + quad * 4 + r;
          int col = bn - 2048 + wcol * 64 + j * 16 + m16;
          Kb[(size_t)row * NKVD + col] = f2bf(acc[i][j][r]);
        }
  } else {
    // swapped layout: row(quad*4+r) = f-tile j, col(m16) = m-tile i
    #pragma unroll
    for (int i = 0; i < 8; i++)
      #pragma unroll
      for (int j = 0; j < 4; j++)
        #pragma unroll
        for (int r = 0; r < 4; r++) {
          int f = bn - 2560 + wcol * 64 + j * 16 + quad * 4 + r;
          int m = bm + wrow * 128 + i * 16 + m16;
          Vt[(size_t)f * MTOT + m] = f2bf(acc[i][j][r]);
        }
  }
}

// ====== O-projection GEMM, 128^2 tile, 4-slot counted-vmcnt ring (round-4) ======
// Port of the verified gemm_qkv ring to 128^2/4-wave: BK=32, slot = A 128x32 +
// B 128x32 = 16 KiB, x4 = 64 KiB (2 blocks/CU). Per-wave 4 loads/stage -> same
// vmcnt arithmetic as gemm_qkv: depth-2 prefetch, steady wait vmcnt(4), never 0.
__global__ __launch_bounds__(256, 2) void gemm_o(
    const unsigned short* __restrict__ A,
    const unsigned short* __restrict__ Bt,
    float* __restrict__ C, int M, int N, int K) {
  __shared__ __align__(16) unsigned short L[4 * 8192];  // 4 slots x 16 KiB
  const int NT = K / 32;         // 64
  int bm = blockIdx.y * 128, bn = blockIdx.x * 128;
  int tid = threadIdx.x, w = tid >> 6, lane = tid & 63;
  int wm = (w >> 1) * 64, wn = (w & 1) * 64;
  int m16 = lane & 15, quad = lane >> 4;
  int lrow = lane >> 2, lch = lane & 3;
  int lchs = lch ^ ((lrow >> 1) & 3);
  int qx = quad ^ ((m16 >> 1) & 3);
  const unsigned short* Ag = A + (size_t)(bm + w * 32 + lrow) * K + lchs * 8;
  const unsigned short* Bg = Bt + (size_t)(bn + w * 32 + lrow) * K + lchs * 8;

  float4v acc[4][4];
  #pragma unroll
  for (int i = 0; i < 4; i++)
    #pragma unroll
    for (int j = 0; j < 4; j++) acc[i][j] = (float4v)0.0f;

  auto stage = [&](int t) {
    unsigned short* Lb = L + (t & 3) * 8192;
    int k0 = t * 32;
    #pragma unroll
    for (int i = 0; i < 2; i++) {
      async16(Ag + (size_t)i * 16 * K + k0, Lb + w * 1024 + i * 512);
      async16(Bg + (size_t)i * 16 * K + k0, Lb + 4096 + w * 1024 + i * 512);
    }
  };

  stage(0); stage(1);
  asm volatile("s_waitcnt vmcnt(4)" ::: "memory");
  __builtin_amdgcn_s_barrier();
  __builtin_amdgcn_sched_barrier(0);

  for (int t = 0; t < NT; ++t) {
    if (t + 2 < NT) stage(t + 2);
    const unsigned short* Ab_ = L + (t & 3) * 8192;
    const unsigned short* Bb_ = Ab_ + 4096;
    short8 af[4], bfr[4];
    #pragma unroll
    for (int i = 0; i < 4; i++)
      af[i] = *(const short8*)(&Ab_[(wm + i * 16 + m16) * 32 + qx * 8]);
    #pragma unroll
    for (int j = 0; j < 4; j++)
      bfr[j] = *(const short8*)(&Bb_[(wn + j * 16 + m16) * 32 + qx * 8]);
    __builtin_amdgcn_s_setprio(1);
    #pragma unroll
    for (int i = 0; i < 4; i++)
      #pragma unroll
      for (int j = 0; j < 4; j++)
        acc[i][j] = __builtin_amdgcn_mfma_f32_16x16x32_bf16(af[i], bfr[j], acc[i][j], 0, 0, 0);
    __builtin_amdgcn_s_setprio(0);
    if (t + 2 < NT) { asm volatile("s_waitcnt vmcnt(4)" ::: "memory"); }
    else            { asm volatile("s_waitcnt vmcnt(0)" ::: "memory"); }
    __builtin_amdgcn_s_barrier();
    __builtin_amdgcn_sched_barrier(0);
  }

  #pragma unroll
  for (int i = 0; i < 4; i++)
    #pragma unroll
    for (int j = 0; j < 4; j++)
      #pragma unroll
      for (int r = 0; r < 4; r++) {
        int row = bm + wm + i * 16 + quad * 4 + r;
        int col = bn + wn + j * 16 + m16;
        C[(size_t)row * N + col] = acc[i][j][r];
      }
}

// ---------------- Flash attention: round-1 measured-best schedule ----------------
// (Restored verbatim: K-dbuf, single V, TOP+MID __syncthreads, T5 setprio,
// T13 defer-max. Measured 66.8 us; the counted-vmcnt (68.6) and single-buffer
// 3/CU (78.5 — grid is only 512 blocks = 2/CU, so extra occupancy can't
// materialize) variants both regressed.)
#define FLASH_TILE(CUR, NXT)                                                  \
  {                                                                           \
    const int ktb = kt * 64;                                                  \
    __syncthreads(); /* TOP: all prior-iter LDS reads done, NXT dead */       \
    {                                                                         \
      const unsigned short* Vg = Vt + vgrow * (size_t)MTOT                    \
                                    + (size_t)b * SEQ + ktb + kcv * 32 + vlch * 8; \
      unsigned short* Vl = Vs + kcv * 4096 + ipv * 512;                       \
      _Pragma("unroll")                                                       \
      for (int i = 0; i < 4; i++) async16(Vg + (size_t)i * 16 * MTOT, Vl + i * 512); \
    }                                                                         \
    if (kt < H) {                                                             \
      const unsigned short* Kg = Kp + (((size_t)b * SEQ + (kt + 1) * 64 + lrow) * NKV + kvh) * HD + w * 32 + vlch * 8; \
      unsigned short* Kl = NXT + w * 2048;                                    \
      _Pragma("unroll")                                                       \
      for (int i = 0; i < 4; i++) async16(Kg + (size_t)i * 16 * NKV * HD, Kl + i * 512); \
    }                                                                         \
    const bool act1 = (ktb <= lmax_w);                                        \
    float4v sacc[2][4];                                                       \
    _Pragma("unroll") for (int s4 = 0; s4 < 4; s4++) {                        \
      sacc[0][s4] = (float4v)0.0f; sacc[1][s4] = (float4v)0.0f; }             \
    __builtin_amdgcn_s_setprio(1);                                            \
    if (act1) {                                                               \
      _Pragma("unroll")                                                       \
      for (int s4 = 0; s4 < 4; s4++)                                          \
        _Pragma("unroll")                                                     \
        for (int c = 0; c < 4; c++) {                                         \
          short8 kf = *(const short8*)(&CUR[c * 2048 + (s4 * 16 + m16) * 32 + qx * 8]); \
          sacc[0][s4] = __builtin_amdgcn_mfma_f32_16x16x32_bf16(kf, qf[0][c], sacc[0][s4], 0, 0, 0); \
          sacc[1][s4] = __builtin_amdgcn_mfma_f32_16x16x32_bf16(kf, qf[1][c], sacc[1][s4], 0, 0, 0); \
        }                                                                     \
    } else {                                                                  \
      _Pragma("unroll")                                                       \
      for (int s4 = 0; s4 < 4; s4++)                                          \
        _Pragma("unroll")                                                     \
        for (int c = 0; c < 4; c++) {                                         \
          short8 kf = *(const short8*)(&CUR[c * 2048 + (s4 * 16 + m16) * 32 + qx * 8]); \
          sacc[0][s4] = __builtin_amdgcn_mfma_f32_16x16x32_bf16(kf, qf[0][c], sacc[0][s4], 0, 0, 0); \
        }                                                                     \
    }                                                                         \
    __builtin_amdgcn_s_setprio(0);                                            \
    _Pragma("unroll")                                                         \
    for (int qs = 0; qs < 2; qs++) {                                          \
      if (qs == 0 || act1) {                                                  \
        const int tb = qs ? L : H;                                            \
        const int qabs = tb * 64 + w * 16 + m16;                              \
        const bool diag = (kt == tb);                                         \
        float sv[4][4]; float mloc = -1e30f;                                  \
        if (diag) {                                                           \
          _Pragma("unroll") for (int s4 = 0; s4 < 4; s4++)                    \
            _Pragma("unroll") for (int r = 0; r < 4; r++) {                   \
              int kabs = ktb + s4 * 16 + quad * 4 + r;                        \
              float t = sacc[qs][s4][r];                                      \
              sv[s4][r] = (kabs > qabs) ? -1e30f : t;                         \
              mloc = fmaxf(mloc, sv[s4][r]); }                                \
        } else {                                                              \
          _Pragma("unroll") for (int s4 = 0; s4 < 4; s4++)                    \
            _Pragma("unroll") for (int r = 0; r < 4; r++) {                   \
              sv[s4][r] = sacc[qs][s4][r]; mloc = fmaxf(mloc, sv[s4][r]); }   \
        }                                                                     \
        mloc *= C1;                                                           \
        mloc = fmaxf(mloc, __shfl_xor(mloc, 16, 64));                         \
        mloc = fmaxf(mloc, __shfl_xor(mloc, 32, 64));                         \
        float mnewS = fmaxf(miS[qs], mloc);                                   \
        const bool defer = (bool)__all(mloc <= miS[qs] + 8.0f);               \
        if (defer) mnewS = miS[qs]; /* T13: keep old max, P bounded by 2^8 */ \
        const int prow = qs * 64 + w * 16 + m16;                              \
        const int psw = prow * 32; const int rx = prow & 7;                   \
        float rs = 0.0f;                                                      \
        _Pragma("unroll") for (int s4 = 0; s4 < 4; s4++) {                    \
          float p0 = EXP2F(__builtin_fmaf(sv[s4][0], C1, -mnewS));            \
          float p1 = EXP2F(__builtin_fmaf(sv[s4][1], C1, -mnewS));            \
          float p2 = EXP2F(__builtin_fmaf(sv[s4][2], C1, -mnewS));            \
          float p3 = EXP2F(__builtin_fmaf(sv[s4][3], C1, -mnewS));            \
          rs += p0 + p1 + p2 + p3;                                            \
          uint2 u;                                                            \
          u.x = (__float_as_uint(p1) & 0xffff0000u) | (__float_as_uint(p0) >> 16); \
          u.y = (__float_as_uint(p3) & 0xffff0000u) | (__float_as_uint(p2) >> 16); \
          int chunkW = s4 * 2 + (quad >> 1);                                  \
          *(uint2*)(&Ps[psw + ((chunkW ^ rx) << 2) + (quad & 1) * 2]) = u;    \
        }                                                                     \
        rs += __shfl_xor(rs, 16, 64);                                         \
        rs += __shfl_xor(rs, 32, 64);                                         \
        if (!defer) {                                                         \
          const float alpha = EXP2F(miS[qs] - mnewS);                         \
          li[qs] *= alpha; miS[qs] = mnewS;                                   \
          _Pragma("unroll") for (int ds = 0; ds < 8; ds++) oacc[ds][qs] *= alpha; \
        }                                                                     \
        li[qs] += rs;                                                         \
      }                                                                       \
    }                                                                         \
    __syncthreads(); /* MID: drains V(kt)+K(kt+1), covered by S+softmax */    \
    {                                                                         \
      const int r0 = w * 16 + m16, r1 = 64 + w * 16 + m16;                    \
      __builtin_amdgcn_s_setprio(1);                                          \
      if (act1) {                                                             \
        _Pragma("unroll")                                                     \
        for (int kc = 0; kc < 2; kc++) {                                      \
          short8 pf0 = *(const short8*)(&Ps[r0 * 32 + (((kc * 4 + quad) ^ (r0 & 7)) << 2)]); \
          short8 pf1 = *(const short8*)(&Ps[r1 * 32 + (((kc * 4 + quad) ^ (r1 & 7)) << 2)]); \
          _Pragma("unroll")                                                   \
          for (int ds = 0; ds < 8; ds++) {                                    \
            short8 vf = *(const short8*)(&Vs[kc * 4096 + (ds * 16 + m16) * 32 + qx * 8]); \
            oacc[ds][0] = __builtin_amdgcn_mfma_f32_16x16x32_bf16(vf, pf0, oacc[ds][0], 0, 0, 0); \
            oacc[ds][1] = __builtin_amdgcn_mfma_f32_16x16x32_bf16(vf, pf1, oacc[ds][1], 0, 0, 0); \
          }                                                                   \
        }                                                                     \
      } else {                                                                \
        _Pragma("unroll")                                                     \
        for (int kc = 0; kc < 2; kc++) {                                      \
          short8 pf0 = *(const short8*)(&Ps[r0 * 32 + (((kc * 4 + quad) ^ (r0 & 7)) << 2)]); \
          _Pragma("unroll")                                                   \
          for (int ds = 0; ds < 8; ds++) {                                    \
            short8 vf = *(const short8*)(&Vs[kc * 4096 + (ds * 16 + m16) * 32 + qx * 8]); \
            oacc[ds][0] = __builtin_amdgcn_mfma_f32_16x16x32_bf16(vf, pf0, oacc[ds][0], 0, 0, 0); \
          }                                                                   \
        }                                                                     \
      }                                                                       \
      __builtin_amdgcn_s_setprio(0);                                          \
    }                                                                         \
  }

__global__ __launch_bounds__(256, 2) void flash_attn(
    const unsigned short* __restrict__ Q,
    const unsigned short* __restrict__ Kp,
    const unsigned short* __restrict__ Vt,
    unsigned short* __restrict__ O) {
  __shared__ unsigned short Ks0[4 * 64 * 32];  // 16 KB [dchunk][key][32d]
  __shared__ unsigned short Ks1[4 * 64 * 32];  // 16 KB
  __shared__ unsigned short Vs[2 * 128 * 32];  // 16 KB [kchunk][d][32seq]
  __shared__ unsigned int   Ps[128 * 32];      // 16 KB swizzled P[q][k/2]

  int bx = blockIdx.x;            // 0..15
  int h  = blockIdx.y;
  int b  = blockIdx.z;
  int kvh = h >> 2;
  int H = 31 - bx, L = bx;
  int tid = threadIdx.x;
  int w = tid >> 6, lane = tid & 63;
  int m16 = lane & 15, quad = lane >> 4;
  int lrow = lane >> 2, lch = lane & 3;
  const int vlch = lch ^ ((lrow >> 1) & 3);   // swizzled staging piece
  const int qx = quad ^ ((m16 >> 1) & 3);     // swizzled read piece
  const int lmax_w = L * 64 + w * 16 + 15;    // qs=1 active while ktb <= lmax_w

  const int kcv = w >> 1, ipv = (w & 1) * 4;
  const size_t vgrow = (size_t)kvh * HD + ipv * 16 + lrow;

  // qs=0 -> H-tile rows [H*64 + w*16, +16); qs=1 -> L-tile rows [L*64 + w*16, +16)
  short8 qf[2][4];
  #pragma unroll
  for (int qs = 0; qs < 2; qs++) {
    int tb = qs ? L : H;
    size_t qbase = (((size_t)b * SEQ + tb * 64 + w * 16 + m16) * NHEADS + h) * HD;
    #pragma unroll
    for (int c = 0; c < 4; c++)
      qf[qs][c] = *(const short8*)(Q + qbase + c * 32 + quad * 8);
  }

  float4v oacc[8][2];
  #pragma unroll
  for (int ds = 0; ds < 8; ds++) { oacc[ds][0] = (float4v)0.0f; oacc[ds][1] = (float4v)0.0f; }
  float miS[2] = {-1e30f, -1e30f}, li[2] = {0.0f, 0.0f};

  // prologue: stage K(0) into Ks0 (drained at first TOP barrier)
  {
    const unsigned short* Kg = Kp + (((size_t)b * SEQ + lrow) * NKV + kvh) * HD + w * 32 + vlch * 8;
    unsigned short* Kl = Ks0 + w * 2048;
    #pragma unroll
    for (int i = 0; i < 4; i++) async16(Kg + (size_t)i * 16 * NKV * HD, Kl + i * 512);
  }

  int kt = 0;
  for (;;) {
    FLASH_TILE(Ks0, Ks1)
    if (++kt > H) break;
    FLASH_TILE(Ks1, Ks0)
    if (++kt > H) break;
  }

  #pragma unroll
  for (int qs = 0; qs < 2; qs++) {
    float inv = 1.0f / li[qs];
    int tb = qs ? L : H;
    int qabs = tb * 64 + w * 16 + m16;
    size_t obase = (((size_t)b * SEQ + qabs) * NHEADS + h) * HD + quad * 4;
    #pragma unroll
    for (int ds = 0; ds < 8; ds++) {
      float v0 = oacc[ds][qs][0] * inv;
      float v1 = oacc[ds][qs][1] * inv;
      float v2 = oacc[ds][qs][2] * inv;
      float v3 = oacc[ds][qs][3] * inv;
      uint2 u;
      u.x = ((unsigned)f2bf(v1) << 16) | f2bf(v0);
      u.y = ((unsigned)f2bf(v3) << 16) | f2bf(v2);
      *(uint2*)(O + obase + ds * 16) = u;
    }
  }
}

extern "C" void kernel_launch(void* const* d_in, const int* in_sizes, int n_in,
                              void* d_out, int out_size, void* d_ws, size_t ws_size,
                              hipStream_t stream) {
  const float* x  = (const float*)d_in[0];
  const float* Wq = (const float*)d_in[1];
  const float* Wk = (const float*)d_in[2];
  const float* Wv = (const float*)d_in[3];
  const float* Wo = (const float*)d_in[4];
  float* out = (float*)d_out;

  unsigned short* ws = (unsigned short*)d_ws;
  unsigned short* xb  = ws;                              // [4096][2048]
  unsigned short* Wqt = xb  + (size_t)MTOT * HIDDEN;     // [2048][2048] (Wqt/Wkt/Wvt contiguous = Wqkvt)
  unsigned short* Wkt = Wqt + (size_t)NQ * HIDDEN;       // [512][2048]
  unsigned short* Wvt = Wkt + (size_t)NKVD * HIDDEN;     // [512][2048]
  unsigned short* Wot = Wvt + (size_t)NKVD * HIDDEN;     // [2048][2048]
  unsigned short* Qb  = Wot + (size_t)NQ * HIDDEN;       // [4096][2048]
  unsigned short* Kb  = Qb  + (size_t)MTOT * NQ;         // [4096][512]
  unsigned short* Vtb = Kb  + (size_t)MTOT * NKVD;       // [512][4096]  (V^T)
  unsigned short* Ab  = Vtb + (size_t)MTOT * NKVD;       // [4096][2048]

  cast_f32_bf16<<<(MTOT * HIDDEN / 4 + 255) / 256, 256, 0, stream>>>(x, xb, MTOT * HIDDEN);
  transpose_cast_all<<<dim3(160, 64), 256, 0, stream>>>(Wq, Wk, Wv, Wo, Wqt, Wkt, Wvt, Wot);

  gemm_qkv<<<dim3(NQKV / 256, MTOT / 256), 512, 0, stream>>>(xb, Wqt, Qb, Kb, Vtb);

  rope_all<<<(MTOT * (NHEADS + NKV) * 64) / 256, 256, 0, stream>>>(Qb, Kb);

  flash_attn<<<dim3(16, NHEADS, BATCH), 256, 0, stream>>>(Qb, Kb, Vtb, Ab);

  gemm_o<<<dim3(HIDDEN / 128, MTOT / 128), 256, 0, stream>>>(Ab, Wot, out, MTOT, HIDDEN, NQ);
}

// Round 6
// 276.065 us; speedup vs baseline: 1.1081x; 1.0371x over previous
//
#include <hip/hip_runtime.h>
#include <hip/hip_bf16.h>
#include <math.h>

#define HIDDEN 2048
#define NHEADS 16
#define NKV 4
#define HD 128
#define SEQ 2048
#define BATCH 2
#define MTOT (BATCH*SEQ)     // 4096
#define NQ (NHEADS*HD)       // 2048
#define NKVD (NKV*HD)        // 512
#define NQKV (NQ + 2*NKVD)   // 3072

typedef __attribute__((ext_vector_type(8))) short short8;
typedef __attribute__((ext_vector_type(4))) float float4v;

#if __has_builtin(__builtin_amdgcn_exp2f)
#define EXP2F __builtin_amdgcn_exp2f
#else
#define EXP2F exp2f
#endif
#define C1 0.1275174f   // (1/sqrt(128)) * log2(e)

static __device__ __forceinline__ unsigned short f2bf(float f) {
  union { float f; unsigned int u; } v; v.f = f;
  unsigned int r = v.u + 0x7FFF + ((v.u >> 16) & 1);
  return (unsigned short)(r >> 16);
}
static __device__ __forceinline__ float bf2f(unsigned short h) {
  union { unsigned int u; float f; } v; v.u = ((unsigned int)h) << 16;
  return v.f;
}

// async global->LDS, 16B per lane; LDS dest = uniform base + lane*16
static __device__ __forceinline__ void async16(const unsigned short* g, unsigned short* l) {
  __builtin_amdgcn_global_load_lds(
      (const __attribute__((address_space(1))) unsigned int*)g,
      (__attribute__((address_space(3))) unsigned int*)l, 16, 0, 0);
}

// ------------- merged prep: cast x (fp32->bf16) + transpose 4 weights ----------
// bx < 8192: cast body (4 elems/thread). bx >= 8192: 32x32 transpose tiles;
// flat index -> (tbx, tby); tbx 0..63 Wq, 64..79 Wk, 80..95 Wv, 96..159 Wo.
__global__ void prep(const float* __restrict__ x, unsigned short* __restrict__ xb,
                     const float* __restrict__ Wq, const float* __restrict__ Wk,
                     const float* __restrict__ Wv, const float* __restrict__ Wo,
                     unsigned short* __restrict__ Wqt, unsigned short* __restrict__ Wkt,
                     unsigned short* __restrict__ Wvt, unsigned short* __restrict__ Wot) {
  __shared__ float tile[32][33];
  int bx = blockIdx.x;
  if (bx < 8192) {
    int i = (bx * 256 + threadIdx.x) * 4;
    float4 v = *(const float4*)(x + i);
    ushort4 o;
    o.x = f2bf(v.x); o.y = f2bf(v.y); o.z = f2bf(v.z); o.w = f2bf(v.w);
    *(ushort4*)(xb + i) = o;
    return;
  }
  int bz = bx - 8192;            // 0..10239
  int tbx = bz % 160, tby = bz / 160;
  const int K = 2048;
  const float* W; unsigned short* Wt; int N; int tn;
  if (tbx < 64)      { W = Wq; Wt = Wqt; N = NQ;     tn = tbx * 32; }
  else if (tbx < 80) { W = Wk; Wt = Wkt; N = NKVD;   tn = (tbx - 64) * 32; }
  else if (tbx < 96) { W = Wv; Wt = Wvt; N = NKVD;   tn = (tbx - 80) * 32; }
  else               { W = Wo; Wt = Wot; N = HIDDEN; tn = (tbx - 96) * 32; }
  int tk = tby * 32;
  int tx = threadIdx.x & 31;
  int ty = threadIdx.x >> 5;  // 0..7
  #pragma unroll
  for (int i = 0; i < 4; i++) {
    int k = tk + ty + i * 8;
    tile[ty + i * 8][tx] = W[(size_t)k * N + tn + tx];
  }
  __syncthreads();
  #pragma unroll
  for (int i = 0; i < 4; i++) {
    int n = tn + ty + i * 8;
    Wt[(size_t)n * K + tk + tx] = f2bf(tile[tx][ty + i * 8]);
  }
}

// ---------------- RoPE in place on K only ([B][S][4][128] bf16) ----------------
// Q-RoPE is fused into flash_attn's register prologue (Q is register-loaded there;
// K goes through global_load_lds and can't be roped in transit).
__global__ void rope_k(unsigned short* __restrict__ Kb) {
  int idx = blockIdx.x * blockDim.x + threadIdx.x;
  int d = idx & 63;
  int hr = idx >> 6;                 // (b*SEQ + s)*NKV + h
  int spos = (hr / NKV) % SEQ;
  size_t base = (size_t)hr * HD;
  float inv = exp2f((float)d * -0.2076205059304601f);  // 10000^(-d/64)
  float ang = (float)spos * inv;
  float sn, cs;
  sincosf(ang, &sn, &cs);
  float q1 = bf2f(Kb[base + d]);
  float q2 = bf2f(Kb[base + d + 64]);
  Kb[base + d]      = f2bf(q1 * cs - q2 * sn);
  Kb[base + d + 64] = f2bf(q2 * cs + q1 * sn);
}

// ======== fused QKV GEMM, 256^2 tile, 16 waves (round-5: TLP fix) ==============
// Diagnosis: 512-thr version had 1 block/CU (128 KiB LDS) = 2 waves/SIMD; wall
// 2475 cyc/iter vs ~1000 busy -> dependency-stall bound. Same tile + ring +
// counted vmcnt, now 1024 threads = 16 waves (4/SIMD), per-wave 64x64 (acc[4][4],
// ~110 VGPR, fits 128-VGPR/4-wave budget). Staging: 1 A + 1 B async16 per thread
// per stage (dest = base + tid*16B, lane-linear ok); depth-2 ring -> steady
// vmcnt(2), tail vmcnt(0). Swizzle invariant LDS[r][c]=G[r][c^((r>>1)&3)] kept
// (staging lchs uses (r>>1)&3, read qx uses (m16>>1)&3; higher row bits drop out).
__global__ __launch_bounds__(1024, 4) void gemm_qkv(
    const unsigned short* __restrict__ A,
    const unsigned short* __restrict__ Bt,
    unsigned short* __restrict__ Qb,
    unsigned short* __restrict__ Kb,
    unsigned short* __restrict__ Vt) {
  // ring slot: [A 256x32 | B 256x32] shorts = 32 KiB; x4 slots = 128 KiB
  __shared__ __align__(16) unsigned short L[4 * 16384];
  const int K = HIDDEN;          // 2048
  const int NT = K / 32;         // 64 K-tiles
  int bm = blockIdx.y * 256, bn = blockIdx.x * 256;
  int tid = threadIdx.x, w = tid >> 6, lane = tid & 63;
  int wrow = w >> 2, wcol = w & 3;           // 4M x 4N wave grid, per-wave 64x64
  int m16 = lane & 15, quad = lane >> 4;
  int r = tid >> 2, lch = tid & 3;           // staging row/chunk (256 rows x 4 chunks)
  int lchs = lch ^ ((r >> 1) & 3);           // swizzled staging piece
  int qx = quad ^ ((m16 >> 1) & 3);          // swizzled read piece
  const unsigned short* Agp = A + (size_t)(bm + r) * K + lchs * 8;
  const unsigned short* Bgp = Bt + (size_t)(bn + r) * K + lchs * 8;

  float4v acc[4][4];
  #pragma unroll
  for (int i = 0; i < 4; i++)
    #pragma unroll
    for (int j = 0; j < 4; j++) acc[i][j] = (float4v)0.0f;

  auto stage = [&](int t) {
    unsigned short* Lb = L + (t & 3) * 16384;
    int k0 = t * 32;
    async16(Agp + k0, Lb + tid * 8);
    async16(Bgp + k0, Lb + 8192 + tid * 8);
  };

  const bool isV = (blockIdx.x >= 10);

  // prologue: tiles 0 and 1 in flight; wait tile 0 (leave tile 1's 2), barrier
  stage(0); stage(1);
  asm volatile("s_waitcnt vmcnt(2)" ::: "memory");
  __builtin_amdgcn_s_barrier();
  __builtin_amdgcn_sched_barrier(0);

  if (!isV) {
    for (int t = 0; t < NT; ++t) {
      if (t + 2 < NT) stage(t + 2);
      const unsigned short* Ab_ = L + (t & 3) * 16384;
      const unsigned short* Bb_ = Ab_ + 8192;
      short8 af[4], bfr[4];
      #pragma unroll
      for (int i = 0; i < 4; i++)
        af[i] = *(const short8*)(&Ab_[(wrow * 64 + i * 16 + m16) * 32 + qx * 8]);
      #pragma unroll
      for (int j = 0; j < 4; j++)
        bfr[j] = *(const short8*)(&Bb_[(wcol * 64 + j * 16 + m16) * 32 + qx * 8]);
      __builtin_amdgcn_s_setprio(1);
      #pragma unroll
      for (int i = 0; i < 4; i++)
        #pragma unroll
        for (int j = 0; j < 4; j++)
          acc[i][j] = __builtin_amdgcn_mfma_f32_16x16x32_bf16(af[i], bfr[j], acc[i][j], 0, 0, 0);
      __builtin_amdgcn_s_setprio(0);
      if (t + 2 < NT) { asm volatile("s_waitcnt vmcnt(2)" ::: "memory"); }
      else            { asm volatile("s_waitcnt vmcnt(0)" ::: "memory"); }
      __builtin_amdgcn_s_barrier();
      __builtin_amdgcn_sched_barrier(0);
    }
  } else {
    for (int t = 0; t < NT; ++t) {
      if (t + 2 < NT) stage(t + 2);
      const unsigned short* Ab_ = L + (t & 3) * 16384;
      const unsigned short* Bb_ = Ab_ + 8192;
      short8 af[4], bfr[4];
      #pragma unroll
      for (int i = 0; i < 4; i++)
        af[i] = *(const short8*)(&Ab_[(wrow * 64 + i * 16 + m16) * 32 + qx * 8]);
      #pragma unroll
      for (int j = 0; j < 4; j++)
        bfr[j] = *(const short8*)(&Bb_[(wcol * 64 + j * 16 + m16) * 32 + qx * 8]);
      __builtin_amdgcn_s_setprio(1);
      #pragma unroll
      for (int i = 0; i < 4; i++)
        #pragma unroll
        for (int j = 0; j < 4; j++)
          acc[i][j] = __builtin_amdgcn_mfma_f32_16x16x32_bf16(bfr[j], af[i], acc[i][j], 0, 0, 0);
      __builtin_amdgcn_s_setprio(0);
      if (t + 2 < NT) { asm volatile("s_waitcnt vmcnt(2)" ::: "memory"); }
      else            { asm volatile("s_waitcnt vmcnt(0)" ::: "memory"); }
      __builtin_amdgcn_s_barrier();
      __builtin_amdgcn_sched_barrier(0);
    }
  }

  if (blockIdx.x < 8) {
    #pragma unroll
    for (int i = 0; i < 4; i++)
      #pragma unroll
      for (int j = 0; j < 4; j++)
        #pragma unroll
        for (int rr = 0; rr < 4; rr++) {
          int row = bm + wrow * 64 + i * 16 + quad * 4 + rr;
          int col = bn + wcol * 64 + j * 16 + m16;
          Qb[(size_t)row * NQ + col] = f2bf(acc[i][j][rr]);
        }
  } else if (!isV) {
    #pragma unroll
    for (int i = 0; i < 4; i++)
      #pragma unroll
      for (int j = 0; j < 4; j++)
        #pragma unroll
        for (int rr = 0; rr < 4; rr++) {
          int row = bm + wrow * 64 + i * 16 + quad * 4 + rr;
          int col = bn - 2048 + wcol * 64 + j * 16 + m16;
          Kb[(size_t)row * NKVD + col] = f2bf(acc[i][j][rr]);
        }
  } else {
    // swapped layout: row(quad*4+rr) = f-tile j, col(m16) = m-tile i
    #pragma unroll
    for (int i = 0; i < 4; i++)
      #pragma unroll
      for (int j = 0; j < 4; j++)
        #pragma unroll
        for (int rr = 0; rr < 4; rr++) {
          int f = bn - 2560 + wcol * 64 + j * 16 + quad * 4 + rr;
          int m = bm + wrow * 64 + i * 16 + m16;
          Vt[(size_t)f * MTOT + m] = f2bf(acc[i][j][rr]);
        }
  }
}

// ====== O-projection GEMM, 128^2 tile, 8 waves (round-5: TLP fix) ==============
// 512 threads = 8 waves (2M x 4N, per-wave 64x32, acc[4][2]); 64 KiB ring ->
// 2 blocks/CU = 4 waves/SIMD. 1 A + 1 B load/thread/stage -> vmcnt(2) steady.
__global__ __launch_bounds__(512, 4) void gemm_o(
    const unsigned short* __restrict__ A,
    const unsigned short* __restrict__ Bt,
    float* __restrict__ C, int M, int N, int K) {
  __shared__ __align__(16) unsigned short L[4 * 8192];  // 4 slots x 16 KiB
  const int NT = K / 32;         // 64
  int bm = blockIdx.y * 128, bn = blockIdx.x * 128;
  int tid = threadIdx.x, w = tid >> 6, lane = tid & 63;
  int wrow = w >> 2, wcol = w & 3;           // per-wave 64 rows x 32 cols
  int m16 = lane & 15, quad = lane >> 4;
  int r = tid >> 2, lch = tid & 3;           // staging: 128 rows x 4 chunks
  int lchs = lch ^ ((r >> 1) & 3);
  int qx = quad ^ ((m16 >> 1) & 3);
  const unsigned short* Agp = A + (size_t)(bm + r) * K + lchs * 8;
  const unsigned short* Bgp = Bt + (size_t)(bn + r) * K + lchs * 8;

  float4v acc[4][2];
  #pragma unroll
  for (int i = 0; i < 4; i++)
    #pragma unroll
    for (int j = 0; j < 2; j++) acc[i][j] = (float4v)0.0f;

  auto stage = [&](int t) {
    unsigned short* Lb = L + (t & 3) * 8192;
    int k0 = t * 32;
    async16(Agp + k0, Lb + tid * 8);
    async16(Bgp + k0, Lb + 4096 + tid * 8);
  };

  stage(0); stage(1);
  asm volatile("s_waitcnt vmcnt(2)" ::: "memory");
  __builtin_amdgcn_s_barrier();
  __builtin_amdgcn_sched_barrier(0);

  for (int t = 0; t < NT; ++t) {
    if (t + 2 < NT) stage(t + 2);
    const unsigned short* Ab_ = L + (t & 3) * 8192;
    const unsigned short* Bb_ = Ab_ + 4096;
    short8 af[4], bfr[2];
    #pragma unroll
    for (int i = 0; i < 4; i++)
      af[i] = *(const short8*)(&Ab_[(wrow * 64 + i * 16 + m16) * 32 + qx * 8]);
    #pragma unroll
    for (int j = 0; j < 2; j++)
      bfr[j] = *(const short8*)(&Bb_[(wcol * 32 + j * 16 + m16) * 32 + qx * 8]);
    __builtin_amdgcn_s_setprio(1);
    #pragma unroll
    for (int i = 0; i < 4; i++)
      #pragma unroll
      for (int j = 0; j < 2; j++)
        acc[i][j] = __builtin_amdgcn_mfma_f32_16x16x32_bf16(af[i], bfr[j], acc[i][j], 0, 0, 0);
    __builtin_amdgcn_s_setprio(0);
    if (t + 2 < NT) { asm volatile("s_waitcnt vmcnt(2)" ::: "memory"); }
    else            { asm volatile("s_waitcnt vmcnt(0)" ::: "memory"); }
    __builtin_amdgcn_s_barrier();
    __builtin_amdgcn_sched_barrier(0);
  }

  #pragma unroll
  for (int i = 0; i < 4; i++)
    #pragma unroll
    for (int j = 0; j < 2; j++)
      #pragma unroll
      for (int rr = 0; rr < 4; rr++) {
        int row = bm + wrow * 64 + i * 16 + quad * 4 + rr;
        int col = bn + wcol * 32 + j * 16 + m16;
        C[(size_t)row * N + col] = acc[i][j][rr];
      }
}

// ---------------- Flash attention: round-1 best schedule + fused Q-RoPE ---------
// Q-RoPE applied in-register at block start: each lane holds dims {c*32+quad*8+e}
// for c=0..3 of its 16 q-rows -> both d and d+64 live in the same lane (c and
// c+2). 32 one-time sincosf/lane, amortized over 17-32 iterations; replaces the
// Q-part of the rope kernel (Qb now holds raw GEMM output).
#define FLASH_TILE(CUR, NXT)                                                  \
  {                                                                           \
    const int ktb = kt * 64;                                                  \
    __syncthreads(); /* TOP: all prior-iter LDS reads done, NXT dead */       \
    {                                                                         \
      const unsigned short* Vg = Vt + vgrow * (size_t)MTOT                    \
                                    + (size_t)b * SEQ + ktb + kcv * 32 + vlch * 8; \
      unsigned short* Vl = Vs + kcv * 4096 + ipv * 512;                       \
      _Pragma("unroll")                                                       \
      for (int i = 0; i < 4; i++) async16(Vg + (size_t)i * 16 * MTOT, Vl + i * 512); \
    }                                                                         \
    if (kt < H) {                                                             \
      const unsigned short* Kg = Kp + (((size_t)b * SEQ + (kt + 1) * 64 + lrow) * NKV + kvh) * HD + w * 32 + vlch * 8; \
      unsigned short* Kl = NXT + w * 2048;                                    \
      _Pragma("unroll")                                                       \
      for (int i = 0; i < 4; i++) async16(Kg + (size_t)i * 16 * NKV * HD, Kl + i * 512); \
    }                                                                         \
    const bool act1 = (ktb <= lmax_w);                                        \
    float4v sacc[2][4];                                                       \
    _Pragma("unroll") for (int s4 = 0; s4 < 4; s4++) {                        \
      sacc[0][s4] = (float4v)0.0f; sacc[1][s4] = (float4v)0.0f; }             \
    __builtin_amdgcn_s_setprio(1);                                            \
    if (act1) {                                                               \
      _Pragma("unroll")                                                       \
      for (int s4 = 0; s4 < 4; s4++)                                          \
        _Pragma("unroll")                                                     \
        for (int c = 0; c < 4; c++) {                                         \
          short8 kf = *(const short8*)(&CUR[c * 2048 + (s4 * 16 + m16) * 32 + qx * 8]); \
          sacc[0][s4] = __builtin_amdgcn_mfma_f32_16x16x32_bf16(kf, qf[0][c], sacc[0][s4], 0, 0, 0); \
          sacc[1][s4] = __builtin_amdgcn_mfma_f32_16x16x32_bf16(kf, qf[1][c], sacc[1][s4], 0, 0, 0); \
        }                                                                     \
    } else {                                                                  \
      _Pragma("unroll")                                                       \
      for (int s4 = 0; s4 < 4; s4++)                                          \
        _Pragma("unroll")                                                     \
        for (int c = 0; c < 4; c++) {                                         \
          short8 kf = *(const short8*)(&CUR[c * 2048 + (s4 * 16 + m16) * 32 + qx * 8]); \
          sacc[0][s4] = __builtin_amdgcn_mfma_f32_16x16x32_bf16(kf, qf[0][c], sacc[0][s4], 0, 0, 0); \
        }                                                                     \
    }                                                                         \
    __builtin_amdgcn_s_setprio(0);                                            \
    _Pragma("unroll")                                                         \
    for (int qs = 0; qs < 2; qs++) {                                          \
      if (qs == 0 || act1) {                                                  \
        const int tb = qs ? L : H;                                            \
        const int qabs = tb * 64 + w * 16 + m16;                              \
        const bool diag = (kt == tb);                                         \
        float sv[4][4]; float mloc = -1e30f;                                  \
        if (diag) {                                                           \
          _Pragma("unroll") for (int s4 = 0; s4 < 4; s4++)                    \
            _Pragma("unroll") for (int rr = 0; rr < 4; rr++) {                \
              int kabs = ktb + s4 * 16 + quad * 4 + rr;                       \
              float t = sacc[qs][s4][rr];                                     \
              sv[s4][rr] = (kabs > qabs) ? -1e30f : t;                        \
              mloc = fmaxf(mloc, sv[s4][rr]); }                               \
        } else {                                                              \
          _Pragma("unroll") for (int s4 = 0; s4 < 4; s4++)                    \
            _Pragma("unroll") for (int rr = 0; rr < 4; rr++) {                \
              sv[s4][rr] = sacc[qs][s4][rr]; mloc = fmaxf(mloc, sv[s4][rr]); } \
        }                                                                     \
        mloc *= C1;                                                           \
        mloc = fmaxf(mloc, __shfl_xor(mloc, 16, 64));                         \
        mloc = fmaxf(mloc, __shfl_xor(mloc, 32, 64));                         \
        float mnewS = fmaxf(miS[qs], mloc);                                   \
        const bool defer = (bool)__all(mloc <= miS[qs] + 8.0f);               \
        if (defer) mnewS = miS[qs]; /* T13: keep old max, P bounded by 2^8 */ \
        const int prow = qs * 64 + w * 16 + m16;                              \
        const int psw = prow * 32; const int rx = prow & 7;                   \
        float rs = 0.0f;                                                      \
        _Pragma("unroll") for (int s4 = 0; s4 < 4; s4++) {                    \
          float p0 = EXP2F(__builtin_fmaf(sv[s4][0], C1, -mnewS));            \
          float p1 = EXP2F(__builtin_fmaf(sv[s4][1], C1, -mnewS));            \
          float p2 = EXP2F(__builtin_fmaf(sv[s4][2], C1, -mnewS));            \
          float p3 = EXP2F(__builtin_fmaf(sv[s4][3], C1, -mnewS));            \
          rs += p0 + p1 + p2 + p3;                                            \
          uint2 u;                                                            \
          u.x = (__float_as_uint(p1) & 0xffff0000u) | (__float_as_uint(p0) >> 16); \
          u.y = (__float_as_uint(p3) & 0xffff0000u) | (__float_as_uint(p2) >> 16); \
          int chunkW = s4 * 2 + (quad >> 1);                                  \
          *(uint2*)(&Ps[psw + ((chunkW ^ rx) << 2) + (quad & 1) * 2]) = u;    \
        }                                                                     \
        rs += __shfl_xor(rs, 16, 64);                                         \
        rs += __shfl_xor(rs, 32, 64);                                         \
        if (!defer) {                                                         \
          const float alpha = EXP2F(miS[qs] - mnewS);                         \
          li[qs] *= alpha; miS[qs] = mnewS;                                   \
          _Pragma("unroll") for (int ds = 0; ds < 8; ds++) oacc[ds][qs] *= alpha; \
        }                                                                     \
        li[qs] += rs;                                                         \
      }                                                                       \
    }                                                                         \
    __syncthreads(); /* MID: drains V(kt)+K(kt+1), covered by S+softmax */    \
    {                                                                         \
      const int r0 = w * 16 + m16, r1 = 64 + w * 16 + m16;                    \
      __builtin_amdgcn_s_setprio(1);                                          \
      if (act1) {                                                             \
        _Pragma("unroll")                                                     \
        for (int kc = 0; kc < 2; kc++) {                                      \
          short8 pf0 = *(const short8*)(&Ps[r0 * 32 + (((kc * 4 + quad) ^ (r0 & 7)) << 2)]); \
          short8 pf1 = *(const short8*)(&Ps[r1 * 32 + (((kc * 4 + quad) ^ (r1 & 7)) << 2)]); \
          _Pragma("unroll")                                                   \
          for (int ds = 0; ds < 8; ds++) {                                    \
            short8 vf = *(const short8*)(&Vs[kc * 4096 + (ds * 16 + m16) * 32 + qx * 8]); \
            oacc[ds][0] = __builtin_amdgcn_mfma_f32_16x16x32_bf16(vf, pf0, oacc[ds][0], 0, 0, 0); \
            oacc[ds][1] = __builtin_amdgcn_mfma_f32_16x16x32_bf16(vf, pf1, oacc[ds][1], 0, 0, 0); \
          }                                                                   \
        }                                                                     \
      } else {                                                                \
        _Pragma("unroll")                                                     \
        for (int kc = 0; kc < 2; kc++) {                                      \
          short8 pf0 = *(const short8*)(&Ps[r0 * 32 + (((kc * 4 + quad) ^ (r0 & 7)) << 2)]); \
          _Pragma("unroll")                                                   \
          for (int ds = 0; ds < 8; ds++) {                                    \
            short8 vf = *(const short8*)(&Vs[kc * 4096 + (ds * 16 + m16) * 32 + qx * 8]); \
            oacc[ds][0] = __builtin_amdgcn_mfma_f32_16x16x32_bf16(vf, pf0, oacc[ds][0], 0, 0, 0); \
          }                                                                   \
        }                                                                     \
      }                                                                       \
      __builtin_amdgcn_s_setprio(0);                                          \
    }                                                                         \
  }

__global__ __launch_bounds__(256, 2) void flash_attn(
    const unsigned short* __restrict__ Q,
    const unsigned short* __restrict__ Kp,
    const unsigned short* __restrict__ Vt,
    unsigned short* __restrict__ O) {
  __shared__ unsigned short Ks0[4 * 64 * 32];  // 16 KB [dchunk][key][32d]
  __shared__ unsigned short Ks1[4 * 64 * 32];  // 16 KB
  __shared__ unsigned short Vs[2 * 128 * 32];  // 16 KB [kchunk][d][32seq]
  __shared__ unsigned int   Ps[128 * 32];      // 16 KB swizzled P[q][k/2]

  int bx = blockIdx.x;            // 0..15
  int h  = blockIdx.y;
  int b  = blockIdx.z;
  int kvh = h >> 2;
  int H = 31 - bx, L = bx;
  int tid = threadIdx.x;
  int w = tid >> 6, lane = tid & 63;
  int m16 = lane & 15, quad = lane >> 4;
  int lrow = lane >> 2, lch = lane & 3;
  const int vlch = lch ^ ((lrow >> 1) & 3);   // swizzled staging piece
  const int qx = quad ^ ((m16 >> 1) & 3);     // swizzled read piece
  const int lmax_w = L * 64 + w * 16 + 15;    // qs=1 active while ktb <= lmax_w

  const int kcv = w >> 1, ipv = (w & 1) * 4;
  const size_t vgrow = (size_t)kvh * HD + ipv * 16 + lrow;

  // qs=0 -> H-tile rows [H*64 + w*16, +16); qs=1 -> L-tile rows [L*64 + w*16, +16)
  short8 qf[2][4];
  #pragma unroll
  for (int qs = 0; qs < 2; qs++) {
    int tb = qs ? L : H;
    size_t qbase = (((size_t)b * SEQ + tb * 64 + w * 16 + m16) * NHEADS + h) * HD;
    #pragma unroll
    for (int c = 0; c < 4; c++)
      qf[qs][c] = *(const short8*)(Q + qbase + c * 32 + quad * 8);
  }
  // fused Q-RoPE (in-register): lane's dims c*32+quad*8+e; pairs (c,c+2) = (d,d+64)
  #pragma unroll
  for (int qs = 0; qs < 2; qs++) {
    int tb = qs ? L : H;
    float spos = (float)(tb * 64 + w * 16 + m16);
    #pragma unroll
    for (int c = 0; c < 2; c++) {
      #pragma unroll
      for (int e = 0; e < 8; e++) {
        int d = c * 32 + quad * 8 + e;
        float inv = exp2f((float)d * -0.2076205059304601f);
        float ang = spos * inv;
        float sn, cs;
        sincosf(ang, &sn, &cs);
        float f1 = bf2f((unsigned short)qf[qs][c][e]);
        float f2 = bf2f((unsigned short)qf[qs][c + 2][e]);
        qf[qs][c][e]     = (short)f2bf(f1 * cs - f2 * sn);
        qf[qs][c + 2][e] = (short)f2bf(f2 * cs + f1 * sn);
      }
    }
  }

  float4v oacc[8][2];
  #pragma unroll
  for (int ds = 0; ds < 8; ds++) { oacc[ds][0] = (float4v)0.0f; oacc[ds][1] = (float4v)0.0f; }
  float miS[2] = {-1e30f, -1e30f}, li[2] = {0.0f, 0.0f};

  // prologue: stage K(0) into Ks0 (drained at first TOP barrier)
  {
    const unsigned short* Kg = Kp + (((size_t)b * SEQ + lrow) * NKV + kvh) * HD + w * 32 + vlch * 8;
    unsigned short* Kl = Ks0 + w * 2048;
    #pragma unroll
    for (int i = 0; i < 4; i++) async16(Kg + (size_t)i * 16 * NKV * HD, Kl + i * 512);
  }

  int kt = 0;
  for (;;) {
    FLASH_TILE(Ks0, Ks1)
    if (++kt > H) break;
    FLASH_TILE(Ks1, Ks0)
    if (++kt > H) break;
  }

  #pragma unroll
  for (int qs = 0; qs < 2; qs++) {
    float inv = 1.0f / li[qs];
    int tb = qs ? L : H;
    int qabs = tb * 64 + w * 16 + m16;
    size_t obase = (((size_t)b * SEQ + qabs) * NHEADS + h) * HD + quad * 4;
    #pragma unroll
    for (int ds = 0; ds < 8; ds++) {
      float v0 = oacc[ds][qs][0] * inv;
      float v1 = oacc[ds][qs][1] * inv;
      float v2 = oacc[ds][qs][2] * inv;
      float v3 = oacc[ds][qs][3] * inv;
      uint2 u;
      u.x = ((unsigned)f2bf(v1) << 16) | f2bf(v0);
      u.y = ((unsigned)f2bf(v3) << 16) | f2bf(v2);
      *(uint2*)(O + obase + ds * 16) = u;
    }
  }
}

extern "C" void kernel_launch(void* const* d_in, const int* in_sizes, int n_in,
                              void* d_out, int out_size, void* d_ws, size_t ws_size,
                              hipStream_t stream) {
  const float* x  = (const float*)d_in[0];
  const float* Wq = (const float*)d_in[1];
  const float* Wk = (const float*)d_in[2];
  const float* Wv = (const float*)d_in[3];
  const float* Wo = (const float*)d_in[4];
  float* out = (float*)d_out;

  unsigned short* ws = (unsigned short*)d_ws;
  unsigned short* xb  = ws;                              // [4096][2048]
  unsigned short* Wqt = xb  + (size_t)MTOT * HIDDEN;     // [2048][2048] (Wqt/Wkt/Wvt contiguous = Wqkvt)
  unsigned short* Wkt = Wqt + (size_t)NQ * HIDDEN;       // [512][2048]
  unsigned short* Wvt = Wkt + (size_t)NKVD * HIDDEN;     // [512][2048]
  unsigned short* Wot = Wvt + (size_t)NKVD * HIDDEN;     // [2048][2048]
  unsigned short* Qb  = Wot + (size_t)NQ * HIDDEN;       // [4096][2048]
  unsigned short* Kb  = Qb  + (size_t)MTOT * NQ;         // [4096][512]
  unsigned short* Vtb = Kb  + (size_t)MTOT * NKVD;       // [512][4096]  (V^T)
  unsigned short* Ab  = Vtb + (size_t)MTOT * NKVD;       // [4096][2048]

  prep<<<8192 + 160 * 64, 256, 0, stream>>>(x, xb, Wq, Wk, Wv, Wo, Wqt, Wkt, Wvt, Wot);

  gemm_qkv<<<dim3(NQKV / 256, MTOT / 256), 1024, 0, stream>>>(xb, Wqt, Qb, Kb, Vtb);

  rope_k<<<(MTOT * NKV * 64) / 256, 256, 0, stream>>>(Kb);

  flash_attn<<<dim3(16, NHEADS, BATCH), 256, 0, stream>>>(Qb, Kb, Vtb, Ab);

  gemm_o<<<dim3(HIDDEN / 128, MTOT / 128), 512, 0, stream>>>(Ab, Wot, out, MTOT, HIDDEN, NQ);
}